// Round 9
// baseline (126342.932 us; speedup 1.0000x reference)
//
#include <hip/hip_runtime.h>
#include <hip/hip_bf16.h>
#include <math.h>

#define NN 2000
#define DD 16
#define BB 64
#define TT 12
#define HH 64

__device__ inline float fin(float v) {
  return (v == v && v > -1e30f && v < 1e30f) ? v : 0.f;
}
__device__ inline float sigmoid_safe(float x) {
  float e = expf(-fabsf(x));
  float s = 1.f / (1.f + e);
  return x >= 0.f ? s : 1.f - s;
}
__device__ inline float tanh_safe(float x) {
  float e = expf(-2.f * fabsf(x));
  float r = (1.f - e) / (1.f + e);
  return x >= 0.f ? r : -r;
}

__global__ void kzero(float* p, int n) {
  int i = blockIdx.x * 256 + threadIdx.x;
  if (i < n) p[i] = 0.f;
}

// ---- A = softmax(relu(E E^T), axis=1); all f32 ----
__global__ __launch_bounds__(256) void ka(const float* __restrict__ E,
                                          float* __restrict__ A) {
  __shared__ float s[NN];
  __shared__ float red[256];
  int n = blockIdx.x;
  float en[DD];
#pragma unroll
  for (int d = 0; d < DD; ++d) en[d] = fin(E[n * DD + d]);
  float lmax = 0.f;
  for (int m = threadIdx.x; m < NN; m += 256) {
    float acc = 0.f;
#pragma unroll
    for (int d = 0; d < DD; ++d) acc += en[d] * fin(E[m * DD + d]);
    acc = fmaxf(acc, 0.f);
    s[m] = acc;
    lmax = fmaxf(lmax, acc);
  }
  red[threadIdx.x] = lmax;
  __syncthreads();
  for (int w = 128; w > 0; w >>= 1) {
    if (threadIdx.x < w) red[threadIdx.x] = fmaxf(red[threadIdx.x], red[threadIdx.x + w]);
    __syncthreads();
  }
  float mx = red[0];
  __syncthreads();
  float lsum = 0.f;
  for (int m = threadIdx.x; m < NN; m += 256) {
    float e = expf(s[m] - mx);
    s[m] = e;
    lsum += e;
  }
  red[threadIdx.x] = lsum;
  __syncthreads();
  for (int w = 128; w > 0; w >>= 1) {
    if (threadIdx.x < w) red[threadIdx.x] += red[threadIdx.x + w];
    __syncthreads();
  }
  float inv = 1.f / red[0];
  for (int m = threadIdx.x; m < NN; m += 256) A[(size_t)n * NN + m] = s[m] * inv;
}

// ---- xb[n*CB + bb] = src[((b0+bb)*TT + t)*NN + n] ----
__global__ void kx(const float* __restrict__ src, float* __restrict__ xb,
                   int t, int b0, int CB) {
  int i = blockIdx.x * 256 + threadIdx.x;
  if (i >= NN * CB) return;
  int bb = i % CB;
  int n = i / CB;
  xb[i] = fin(src[((size_t)(b0 + bb) * TT + t) * NN + n]);
}

// ---- C(NN x cols) = A @ V ; f32. 64x64 tile, K=32 ----
#define TM 64
#define TK 32
__global__ __launch_bounds__(256) void kg(const float* __restrict__ A,
                                          const float* __restrict__ V,
                                          float* __restrict__ C, int cols) {
  __shared__ float As[TK][TM + 1];
  __shared__ float Bs[TK][TM + 1];
  int r0 = blockIdx.x * TM;
  int c0 = blockIdx.y * TM;
  int tid = threadIdx.x;
  int tx = tid % 16;
  int ty = tid / 16;
  float acc[4][4];
#pragma unroll
  for (int i = 0; i < 4; ++i)
#pragma unroll
    for (int j = 0; j < 4; ++j) acc[i][j] = 0.f;
  for (int k0 = 0; k0 < NN; k0 += TK) {
    for (int i = tid; i < TM * TK; i += 256) {
      int rr = i / TK, kk = i % TK;
      int gr = r0 + rr, gk = k0 + kk;
      As[kk][rr] = (gr < NN && gk < NN) ? A[(size_t)gr * NN + gk] : 0.f;
    }
    for (int i = tid; i < TK * TM; i += 256) {
      int kk = i / TM, cc = i % TM;
      int gk = k0 + kk, gc = c0 + cc;
      Bs[kk][cc] = (gk < NN && gc < cols) ? V[(size_t)gk * cols + gc] : 0.f;
    }
    __syncthreads();
#pragma unroll 4
    for (int kk = 0; kk < TK; ++kk) {
      float a[4], b[4];
#pragma unroll
      for (int i = 0; i < 4; ++i) a[i] = As[kk][ty * 4 + i];
#pragma unroll
      for (int j = 0; j < 4; ++j) b[j] = Bs[kk][tx * 4 + j];
#pragma unroll
      for (int i = 0; i < 4; ++i)
#pragma unroll
        for (int j = 0; j < 4; ++j) acc[i][j] += a[i] * b[j];
    }
    __syncthreads();
  }
#pragma unroll
  for (int i = 0; i < 4; ++i) {
    int gr = r0 + ty * 4 + i;
    if (gr >= NN) continue;
#pragma unroll
    for (int j = 0; j < 4; ++j) {
      int gc = c0 + tx * 4 + j;
      if (gc < cols) C[(size_t)gr * cols + gc] = acc[i][j];
    }
  }
}

// ---- p[i] = 2*p[i] - x0[i]  (Chebyshev k=2 term, in place) ----
__global__ void kcheb(float* __restrict__ p, const float* __restrict__ x0, int n) {
  int i = blockIdx.x * 256 + threadIdx.x;
  if (i < n) p[i] = 2.f * p[i] - x0[i];
}

// ---- zb[i] = zb[i] * h[i]  (u = z .* h, in place into zb) ----
__global__ void kmulz(float* __restrict__ zb, const float* __restrict__ h, int n) {
  int i = blockIdx.x * 256 + threadIdx.x;
  if (i < n) zb[i] = zb[i] * h[i];
}

// ---- gconv: out[n,b,o] (+)= sum_k sum_c xk[n,b,c] * (sum_d E[n,d] wp[d,k,base+c,o])
// act: 0 none, 1 sigmoid, 2 tanh.  accum: read-add dst.
// update: h = r*h + (1-r)*res instead of storing.
template <int O, int CB>
__global__ __launch_bounds__(256) void kgc(
    const float* __restrict__ x0, const float* __restrict__ x1, const float* __restrict__ x2,
    const float* __restrict__ wp, int Ctot, int base_c, int nC,
    const float* __restrict__ E, const float* __restrict__ bp,
    int act, int accum, float* outA, float* outB,
    int update, const float* __restrict__ rb, float* hio) {
  __shared__ float xs[8][CB + 1];
  __shared__ float ws[8][O];
  __shared__ float esm[DD];
  int n = blockIdx.x;
  int tid = threadIdx.x;
  int to = tid % 16;
  int tb = tid / 16;
  if (tid < DD) esm[tid] = fin(E[n * DD + tid]);
  __syncthreads();
  constexpr int NO = O / 16;
  constexpr int NB = CB / 16;
  float acc[NB][NO];
#pragma unroll
  for (int i = 0; i < NB; ++i)
#pragma unroll
    for (int j = 0; j < NO; ++j) acc[i][j] = 0.f;
  const size_t nb = (size_t)n * CB;
  for (int k = 0; k < 3; ++k) {
    const float* xk = (k == 0) ? x0 : (k == 1) ? x1 : x2;
    for (int c0 = 0; c0 < nC; c0 += 8) {
      int chunk = (nC - c0 < 8) ? (nC - c0) : 8;
      for (int i = tid; i < chunk * CB; i += 256) {
        int cc = i % chunk;
        int b = i / chunk;
        xs[cc][b] = xk[(nb + b) * nC + c0 + cc];
      }
      for (int i = tid; i < chunk * O; i += 256) {
        int o = i % O;
        int cc = i / O;
        int crow = base_c + c0 + cc;
        float wa = 0.f;
#pragma unroll
        for (int d = 0; d < DD; ++d)
          wa += esm[d] * fin(wp[((size_t)(d * 3 + k) * Ctot + crow) * O + o]);
        ws[cc][o] = wa;
      }
      __syncthreads();
      for (int cc = 0; cc < chunk; ++cc) {
        float xv[NB];
#pragma unroll
        for (int i = 0; i < NB; ++i) xv[i] = xs[cc][tb + 16 * i];
#pragma unroll
        for (int j = 0; j < NO; ++j) {
          float wv = ws[cc][to + 16 * j];
#pragma unroll
          for (int i = 0; i < NB; ++i) acc[i][j] += xv[i] * wv;
        }
      }
      __syncthreads();
    }
  }
#pragma unroll
  for (int i2 = 0; i2 < NB; ++i2) {
    int b = tb + 16 * i2;
#pragma unroll
    for (int j = 0; j < NO; ++j) {
      int o = to + 16 * j;
      float r = acc[i2][j];
      float* dst = (o < HH || !outB) ? (outA + (nb + b) * HH + (o % HH))
                                     : (outB + (nb + b) * HH + (o - HH));
      if (accum) r += *dst;
      if (bp) {
        float ba = 0.f;
#pragma unroll
        for (int d = 0; d < DD; ++d) ba += esm[d] * fin(bp[d * O + o]);
        r += ba;
      }
      r = fin(r);
      if (act == 1) r = sigmoid_safe(r);
      else if (act == 2) r = tanh_safe(r);
      if (update) {
        float rg = rb[(nb + b) * HH + o];
        float hold = hio[(nb + b) * HH + o];
        hio[(nb + b) * HH + o] = rg * hold + (1.f - rg) * r;
      } else {
        *dst = r;
      }
    }
  }
}

// ---- out[(b0+bb), o, n] = sum_h h1[n,bb,h]*cw[o*H+h] + cb[o] ----
__global__ void kfin(const float* __restrict__ h1, const float* __restrict__ cw,
                     const float* __restrict__ cb, float* __restrict__ out,
                     int b0, int CB) {
  int idx = blockIdx.x * 256 + threadIdx.x;
  if (idx >= CB * TT * NN) return;
  int n = idx % NN;
  int o = (idx / NN) % TT;
  int bb = idx / (NN * TT);
  const float* hp = h1 + ((size_t)n * CB + bb) * HH;
  float acc = fin(cb[o]);
#pragma unroll
  for (int hh = 0; hh < HH; ++hh) acc += hp[hh] * fin(cw[o * HH + hh]);
  out[((size_t)(b0 + bb) * TT + o) * NN + n] = fin(acc);
}

template <int CB>
static void run_chunks(const float* src, const float* E,
                       const float* gwp0, const float* gbp0,
                       const float* uwp0, const float* ubp0,
                       const float* gwp1, const float* gbp1,
                       const float* uwp1, const float* ubp1,
                       const float* cw, const float* cb,
                       float* out, float* A, char* wsp, size_t off0,
                       hipStream_t stream) {
  size_t off = off0;
  auto alloc = [&](size_t nelem) {
    float* p = (float*)(wsp + off);
    off += (nelem * 4 + 255) & ~(size_t)255;
    return p;
  };
  const size_t NBH_C = (size_t)NN * CB * HH;
  float* P1  = alloc(NBH_C);
  float* P2  = alloc(NBH_C);
  float* h0  = alloc(NBH_C);
  float* h1  = alloc(NBH_C);
  float* zb  = alloc(NBH_C);
  float* rbf = alloc(NBH_C);
  float* hc  = alloc(NBH_C);
  float* xb0 = alloc((size_t)NN * CB);
  float* xb1 = alloc((size_t)NN * CB);
  float* xb2 = alloc((size_t)NN * CB);

  const int EW = (int)((NBH_C + 255) / 256);
  const int EWS = (NN * CB + 255) / 256;
  const dim3 gBig((NN + TM - 1) / TM, (CB * HH) / TM);
  const dim3 gSm((NN + TM - 1) / TM, (CB + TM - 1) / TM);
  float* nul = nullptr;
  auto gemmB = [&](const float* Vv, float* Cc) {
    kg<<<gBig, 256, 0, stream>>>(A, Vv, Cc, CB * HH);
  };
  auto gemmS = [&](const float* Vv, float* Cc) {
    kg<<<gSm, 256, 0, stream>>>(A, Vv, Cc, CB);
  };

  for (int b0 = 0; b0 < BB; b0 += CB) {
    kzero<<<EW, 256, 0, stream>>>(h0, (int)NBH_C);
    kzero<<<EW, 256, 0, stream>>>(h1, (int)NBH_C);
    for (int t = 0; t < TT; ++t) {
      // ===== layer 0 (x = src slice, Cin=1, Ctot=65) =====
      kx<<<EWS, 256, 0, stream>>>(src, xb0, t, b0, CB);
      gemmS(xb0, xb1);
      gemmS(xb1, xb2);
      kcheb<<<EWS, 256, 0, stream>>>(xb2, xb0, NN * CB);
      gemmB(h0, P1);
      gemmB(P1, P2);
      kcheb<<<EW, 256, 0, stream>>>(P2, h0, (int)NBH_C);
      kgc<128, CB><<<NN, 256, 0, stream>>>(h0, P1, P2, gwp0, 65, 1, 64, E, nullptr,
                                           0, 0, zb, rbf, 0, nul, nul);
      kgc<128, CB><<<NN, 256, 0, stream>>>(xb0, xb1, xb2, gwp0, 65, 0, 1, E, gbp0,
                                           1, 1, zb, rbf, 0, nul, nul);
      kgc<64, CB><<<NN, 256, 0, stream>>>(xb0, xb1, xb2, uwp0, 65, 0, 1, E, nullptr,
                                          0, 0, hc, nul, 0, nul, nul);
      kmulz<<<EW, 256, 0, stream>>>(zb, h0, (int)NBH_C);
      gemmB(zb, P1);
      gemmB(P1, P2);
      kcheb<<<EW, 256, 0, stream>>>(P2, zb, (int)NBH_C);
      kgc<64, CB><<<NN, 256, 0, stream>>>(zb, P1, P2, uwp0, 65, 1, 64, E, ubp0,
                                          2, 1, hc, nul, 1, rbf, h0);
      // ===== layer 1 (x = h0, Cin=64, Ctot=128) =====
      gemmB(h1, P1);
      gemmB(P1, P2);
      kcheb<<<EW, 256, 0, stream>>>(P2, h1, (int)NBH_C);
      kgc<128, CB><<<NN, 256, 0, stream>>>(h1, P1, P2, gwp1, 128, 64, 64, E, nullptr,
                                           0, 0, zb, rbf, 0, nul, nul);
      gemmB(h0, P1);
      gemmB(P1, P2);
      kcheb<<<EW, 256, 0, stream>>>(P2, h0, (int)NBH_C);
      kgc<128, CB><<<NN, 256, 0, stream>>>(h0, P1, P2, gwp1, 128, 0, 64, E, gbp1,
                                           1, 1, zb, rbf, 0, nul, nul);
      kgc<64, CB><<<NN, 256, 0, stream>>>(h0, P1, P2, uwp1, 128, 0, 64, E, nullptr,
                                          0, 0, hc, nul, 0, nul, nul);
      kmulz<<<EW, 256, 0, stream>>>(zb, h1, (int)NBH_C);
      gemmB(zb, P1);
      gemmB(P1, P2);
      kcheb<<<EW, 256, 0, stream>>>(P2, zb, (int)NBH_C);
      kgc<64, CB><<<NN, 256, 0, stream>>>(zb, P1, P2, uwp1, 128, 64, 64, E, ubp1,
                                          2, 1, hc, nul, 1, rbf, h1);
    }
    kfin<<<(CB * TT * NN + 255) / 256, 256, 0, stream>>>(h1, cw, cb, out, b0, CB);
  }
}

extern "C" void kernel_launch(void* const* d_in, const int* in_sizes, int n_in,
                              void* d_out, int out_size, void* d_ws, size_t ws_size,
                              hipStream_t stream) {
  const float* src  = (const float*)d_in[0];
  const float* E    = (const float*)d_in[1];
  const float* gwp0 = (const float*)d_in[2];
  const float* gbp0 = (const float*)d_in[3];
  const float* uwp0 = (const float*)d_in[4];
  const float* ubp0 = (const float*)d_in[5];
  const float* gwp1 = (const float*)d_in[6];
  const float* gbp1 = (const float*)d_in[7];
  const float* uwp1 = (const float*)d_in[8];
  const float* ubp1 = (const float*)d_in[9];
  const float* cw   = (const float*)d_in[10];
  const float* cb   = (const float*)d_in[11];
  float* out = (float*)d_out;
  (void)in_sizes; (void)n_in; (void)out_size;

  char* wsp = (char*)d_ws;
  float* A = (float*)wsp;                       // NN*NN f32 = 16.0 MB
  size_t off0 = ((size_t)NN * NN * 4 + 255) & ~(size_t)255;

  ka<<<NN, 256, 0, stream>>>(E, A);

  // footprints: CB=64 -> 245.8 MB, CB=32 -> 131.5 MB, CB=16 -> 74.2 MB
  if (ws_size >= (size_t)255 * 1000 * 1000) {
    run_chunks<64>(src, E, gwp0, gbp0, uwp0, ubp0, gwp1, gbp1, uwp1, ubp1,
                   cw, cb, out, A, wsp, off0, stream);
  } else if (ws_size >= (size_t)140 * 1000 * 1000) {
    run_chunks<32>(src, E, gwp0, gbp0, uwp0, ubp0, gwp1, gbp1, uwp1, ubp1,
                   cw, cb, out, A, wsp, off0, stream);
  } else {
    run_chunks<16>(src, E, gwp0, gbp0, uwp0, ubp0, gwp1, gbp1, uwp1, ubp1,
                   cw, cb, out, A, wsp, off0, stream);
  }
}

// Round 11
// 83161.414 us; speedup vs baseline: 1.5192x; 1.5192x over previous
//
#include <hip/hip_runtime.h>
#include <hip/hip_bf16.h>
#include <math.h>

#define NN 2000
#define DD 16
#define BB 64
#define TT 12
#define HH 64
#define MR 4000   // rows of stacked M = [A ; 2A^2 - I]
#define SCL 2048.0f
#define ISCL (1.0f / 2048.0f)

typedef _Float16 f16;
typedef __attribute__((ext_vector_type(8))) _Float16 frag8h;  // 8 f16 = 4 VGPRs
typedef __attribute__((ext_vector_type(4))) float floatx4;

__device__ inline float fin(float v) {
  return (v == v && v > -1e30f && v < 1e30f) ? v : 0.f;
}
__device__ inline float sigmoid_safe(float x) {
  float e = expf(-fabsf(x));
  float s = 1.f / (1.f + e);
  return x >= 0.f ? s : 1.f - s;
}
__device__ inline float tanh_safe(float x) {
  float e = expf(-2.f * fabsf(x));
  float r = (1.f - e) / (1.f + e);
  return x >= 0.f ? r : -r;
}
// split v = hi + lo/2048, hi/lo f16
__device__ inline void split16(float v, f16& hi, f16& lo) {
  hi = (f16)v;
  lo = (f16)((v - (float)hi) * SCL);
}

__global__ void kzero(float* p, int n) {
  int i = blockIdx.x * 256 + threadIdx.x;
  if (i < n) p[i] = 0.f;
}

// ---- A = softmax(relu(E E^T), axis=1); all f32 ----
__global__ __launch_bounds__(256) void ka(const float* __restrict__ E,
                                          float* __restrict__ A) {
  __shared__ float s[NN];
  __shared__ float red[256];
  int n = blockIdx.x;
  float en[DD];
#pragma unroll
  for (int d = 0; d < DD; ++d) en[d] = fin(E[n * DD + d]);
  float lmax = 0.f;
  for (int m = threadIdx.x; m < NN; m += 256) {
    float acc = 0.f;
#pragma unroll
    for (int d = 0; d < DD; ++d) acc += en[d] * fin(E[m * DD + d]);
    acc = fmaxf(acc, 0.f);
    s[m] = acc;
    lmax = fmaxf(lmax, acc);
  }
  red[threadIdx.x] = lmax;
  __syncthreads();
  for (int w = 128; w > 0; w >>= 1) {
    if (threadIdx.x < w) red[threadIdx.x] = fmaxf(red[threadIdx.x], red[threadIdx.x + w]);
    __syncthreads();
  }
  float mx = red[0];
  __syncthreads();
  float lsum = 0.f;
  for (int m = threadIdx.x; m < NN; m += 256) {
    float e = expf(s[m] - mx);
    s[m] = e;
    lsum += e;
  }
  red[threadIdx.x] = lsum;
  __syncthreads();
  for (int w = 128; w > 0; w >>= 1) {
    if (threadIdx.x < w) red[threadIdx.x] += red[threadIdx.x + w];
    __syncthreads();
  }
  float inv = 1.f / red[0];
  for (int m = threadIdx.x; m < NN; m += 256) A[(size_t)n * NN + m] = s[m] * inv;
}

// ---- C(NN x cols) = A @ V ; f32, 64x64 tile (prologue only, for A^2) ----
#define TM 64
#define TK 32
__global__ __launch_bounds__(256) void kg(const float* __restrict__ A,
                                          const float* __restrict__ V,
                                          float* __restrict__ C, int cols) {
  __shared__ float As[TK][TM + 1];
  __shared__ float Bs[TK][TM + 1];
  int r0 = blockIdx.x * TM;
  int c0 = blockIdx.y * TM;
  int tid = threadIdx.x;
  int tx = tid % 16;
  int ty = tid / 16;
  float acc[4][4];
#pragma unroll
  for (int i = 0; i < 4; ++i)
#pragma unroll
    for (int j = 0; j < 4; ++j) acc[i][j] = 0.f;
  for (int k0 = 0; k0 < NN; k0 += TK) {
    for (int i = tid; i < TM * TK; i += 256) {
      int rr = i / TK, kk = i % TK;
      int gr = r0 + rr, gk = k0 + kk;
      As[kk][rr] = (gr < NN && gk < NN) ? A[(size_t)gr * NN + gk] : 0.f;
    }
    for (int i = tid; i < TK * TM; i += 256) {
      int kk = i / TM, cc = i % TM;
      int gk = k0 + kk, gc = c0 + cc;
      Bs[kk][cc] = (gk < NN && gc < cols) ? V[(size_t)gk * cols + gc] : 0.f;
    }
    __syncthreads();
#pragma unroll 4
    for (int kk = 0; kk < TK; ++kk) {
      float a[4], b[4];
#pragma unroll
      for (int i = 0; i < 4; ++i) a[i] = As[kk][ty * 4 + i];
#pragma unroll
      for (int j = 0; j < 4; ++j) b[j] = Bs[kk][tx * 4 + j];
#pragma unroll
      for (int i = 0; i < 4; ++i)
#pragma unroll
        for (int j = 0; j < 4; ++j) acc[i][j] += a[i] * b[j];
    }
    __syncthreads();
  }
#pragma unroll
  for (int i = 0; i < 4; ++i) {
    int gr = r0 + ty * 4 + i;
    if (gr >= NN) continue;
#pragma unroll
    for (int j = 0; j < 4; ++j) {
      int gc = c0 + tx * 4 + j;
      if (gc < cols) C[(size_t)gr * cols + gc] = acc[i][j];
    }
  }
}

// ---- build split M = [A ; 2A^2 - I] as f16 hi + lo/2048 ----
__global__ void ksplitM(const float* __restrict__ A, const float* __restrict__ A2,
                        f16* __restrict__ Mh, f16* __restrict__ Ml) {
  int i = blockIdx.x * 256 + threadIdx.x;
  if (i >= MR * NN) return;
  int m = i / NN;
  int k = i % NN;
  float v;
  if (m < NN) v = A[(size_t)m * NN + k];
  else {
    int mm = m - NN;
    v = 2.f * A2[(size_t)mm * NN + k] - (mm == k ? 1.f : 0.f);
  }
  f16 hi, lo;
  split16(v, hi, lo);
  Mh[i] = hi;
  Ml[i] = lo;
}

// ---- split+transpose: V f32 [2000][cols] -> Th/Tl f16 [cols][2000] ----
__global__ __launch_bounds__(256) void kconvT(const float* __restrict__ V,
                                              f16* __restrict__ Th,
                                              f16* __restrict__ Tl, int cols) {
  __shared__ float sh[32][33];
  int k0 = blockIdx.x * 32;
  int c0 = blockIdx.y * 32;
  int tx = threadIdx.x % 32;
  int ty = threadIdx.x / 32;  // 0..7
#pragma unroll
  for (int i = 0; i < 4; ++i) {
    int r = k0 + ty + i * 8;
    int c = c0 + tx;
    sh[ty + i * 8][tx] = (r < NN && c < cols) ? V[(size_t)r * cols + c] : 0.f;
  }
  __syncthreads();
#pragma unroll
  for (int i = 0; i < 4; ++i) {
    int cc = c0 + ty + i * 8;
    int kk = k0 + tx;
    if (cc < cols && kk < NN) {
      f16 hi, lo;
      split16(sh[tx][ty + i * 8], hi, lo);
      Th[(size_t)cc * NN + kk] = hi;
      Tl[(size_t)cc * NN + kk] = lo;
    }
  }
}

// ---- MFMA GEMM: C = (Mh + Ml/2048) @ (Bh + Bl/2048), dropping Ml@Bl.
// acc0 = Mh@Bh ; acc1 = Mh@Bl + Ml@Bh ; C = acc0 + acc1/2048.
// Block tile 128x64, 4 waves (2x2), per-wave 64x32. Single K pass, fused phases.
#define LDK 40
__global__ __launch_bounds__(256) void kmm(const f16* __restrict__ Mh,
                                           const f16* __restrict__ Ml,
                                           const f16* __restrict__ Bh,
                                           const f16* __restrict__ Bl,
                                           float* __restrict__ C1,
                                           float* __restrict__ C2, int cols) {
  __shared__ f16 Ash[128 * LDK];
  __shared__ f16 Asl[128 * LDK];
  __shared__ f16 Bsh[64 * LDK];
  __shared__ f16 Bsl[64 * LDK];
  int tid = threadIdx.x;
  int lane = tid & 63;
  int wave = tid >> 6;
  int wr = wave >> 1;   // 0..1 (64-row half)
  int wc = wave & 1;    // 0..1 (32-col half)
  int bx = blockIdx.x;
  int by = blockIdx.y;
  floatx4 acc0[4][2], acc1[4][2];
#pragma unroll
  for (int i = 0; i < 4; ++i)
#pragma unroll
    for (int j = 0; j < 2; ++j) {
      acc0[i][j] = (floatx4){0.f, 0.f, 0.f, 0.f};
      acc1[i][j] = (floatx4){0.f, 0.f, 0.f, 0.f};
    }
  const frag8h zf = {0, 0, 0, 0, 0, 0, 0, 0};

  for (int k0 = 0; k0 < NN; k0 += 32) {
    // stage A tiles (128x32, hi+lo): 512 chunks each
    for (int c = tid; c < 512; c += 256) {
      int r = c >> 2;
      int ko = (c & 3) << 3;
      int gr = bx * 128 + r;
      int gk = k0 + ko;
      bool ok = (gr < MR) && (gk + 8 <= NN);
      size_t gidx = (size_t)gr * NN + gk;
      *(frag8h*)(&Ash[r * LDK + ko]) = ok ? *(const frag8h*)(Mh + gidx) : zf;
      *(frag8h*)(&Asl[r * LDK + ko]) = ok ? *(const frag8h*)(Ml + gidx) : zf;
    }
    // stage B tiles (64x32, hi+lo): 256 chunks each
    {
      int c = tid;
      if (c < 256) {
        int r = c >> 2;
        int ko = (c & 3) << 3;
        int gc = by * 64 + r;
        int gk = k0 + ko;
        bool ok = (gc < cols) && (gk + 8 <= NN);
        size_t gidx = (size_t)gc * NN + gk;
        *(frag8h*)(&Bsh[r * LDK + ko]) = ok ? *(const frag8h*)(Bh + gidx) : zf;
        *(frag8h*)(&Bsl[r * LDK + ko]) = ok ? *(const frag8h*)(Bl + gidx) : zf;
      }
    }
    __syncthreads();
    int koff = (lane >> 4) * 8;
    frag8h ah[4], al[4], bh[2], bl[2];
#pragma unroll
    for (int mi = 0; mi < 4; ++mi) {
      int row = wr * 64 + mi * 16 + (lane & 15);
      ah[mi] = *(const frag8h*)(&Ash[row * LDK + koff]);
      al[mi] = *(const frag8h*)(&Asl[row * LDK + koff]);
    }
#pragma unroll
    for (int ni = 0; ni < 2; ++ni) {
      int col = wc * 32 + ni * 16 + (lane & 15);
      bh[ni] = *(const frag8h*)(&Bsh[col * LDK + koff]);
      bl[ni] = *(const frag8h*)(&Bsl[col * LDK + koff]);
    }
#pragma unroll
    for (int mi = 0; mi < 4; ++mi)
#pragma unroll
      for (int ni = 0; ni < 2; ++ni) {
        acc0[mi][ni] = __builtin_amdgcn_mfma_f32_16x16x32_f16(ah[mi], bh[ni], acc0[mi][ni], 0, 0, 0);
        acc1[mi][ni] = __builtin_amdgcn_mfma_f32_16x16x32_f16(ah[mi], bl[ni], acc1[mi][ni], 0, 0, 0);
        acc1[mi][ni] = __builtin_amdgcn_mfma_f32_16x16x32_f16(al[mi], bh[ni], acc1[mi][ni], 0, 0, 0);
      }
    __syncthreads();
  }
  // store: C/D layout col = lane&15, row = (lane>>4)*4 + reg
#pragma unroll
  for (int mi = 0; mi < 4; ++mi) {
#pragma unroll
    for (int ni = 0; ni < 2; ++ni) {
#pragma unroll
      for (int reg = 0; reg < 4; ++reg) {
        int row = bx * 128 + wr * 64 + mi * 16 + (lane >> 4) * 4 + reg;
        int col = by * 64 + wc * 32 + ni * 16 + (lane & 15);
        if (col >= cols || row >= MR) continue;
        float v = acc0[mi][ni][reg] + acc1[mi][ni][reg] * ISCL;
        if (row < NN) C1[(size_t)row * cols + col] = v;
        else C2[(size_t)(row - NN) * cols + col] = v;
      }
    }
  }
}

// ---- xb[n*CB + bb] = src[((b0+bb)*TT + t)*NN + n] ----
__global__ void kx(const float* __restrict__ src, float* __restrict__ xb,
                   int t, int b0, int CB) {
  int i = blockIdx.x * 256 + threadIdx.x;
  if (i >= NN * CB) return;
  int bb = i % CB;
  int n = i / CB;
  xb[i] = fin(src[((size_t)(b0 + bb) * TT + t) * NN + n]);
}

// ---- zb[i] *= h[i] ----
__global__ void kmulz(float* __restrict__ zb, const float* __restrict__ h, int n) {
  int i = blockIdx.x * 256 + threadIdx.x;
  if (i < n) zb[i] = zb[i] * h[i];
}

// ---- gconv (unchanged from passing R9) ----
template <int O, int CB>
__global__ __launch_bounds__(256) void kgc(
    const float* __restrict__ x0, const float* __restrict__ x1, const float* __restrict__ x2,
    const float* __restrict__ wp, int Ctot, int base_c, int nC,
    const float* __restrict__ E, const float* __restrict__ bp,
    int act, int accum, float* outA, float* outB,
    int update, const float* __restrict__ rb, float* hio) {
  __shared__ float xs[8][CB + 1];
  __shared__ float ws[8][O];
  __shared__ float esm[DD];
  int n = blockIdx.x;
  int tid = threadIdx.x;
  int to = tid % 16;
  int tb = tid / 16;
  if (tid < DD) esm[tid] = fin(E[n * DD + tid]);
  __syncthreads();
  constexpr int NO = O / 16;
  constexpr int NB = CB / 16;
  float acc[NB][NO];
#pragma unroll
  for (int i = 0; i < NB; ++i)
#pragma unroll
    for (int j = 0; j < NO; ++j) acc[i][j] = 0.f;
  const size_t nb = (size_t)n * CB;
  for (int k = 0; k < 3; ++k) {
    const float* xk = (k == 0) ? x0 : (k == 1) ? x1 : x2;
    for (int c0 = 0; c0 < nC; c0 += 8) {
      int chunk = (nC - c0 < 8) ? (nC - c0) : 8;
      for (int i = tid; i < chunk * CB; i += 256) {
        int cc = i % chunk;
        int b = i / chunk;
        xs[cc][b] = xk[(nb + b) * nC + c0 + cc];
      }
      for (int i = tid; i < chunk * O; i += 256) {
        int o = i % O;
        int cc = i / O;
        int crow = base_c + c0 + cc;
        float wa = 0.f;
#pragma unroll
        for (int d = 0; d < DD; ++d)
          wa += esm[d] * fin(wp[((size_t)(d * 3 + k) * Ctot + crow) * O + o]);
        ws[cc][o] = wa;
      }
      __syncthreads();
      for (int cc = 0; cc < chunk; ++cc) {
        float xv[NB];
#pragma unroll
        for (int i = 0; i < NB; ++i) xv[i] = xs[cc][tb + 16 * i];
#pragma unroll
        for (int j = 0; j < NO; ++j) {
          float wv = ws[cc][to + 16 * j];
#pragma unroll
          for (int i = 0; i < NB; ++i) acc[i][j] += xv[i] * wv;
        }
      }
      __syncthreads();
    }
  }
#pragma unroll
  for (int i2 = 0; i2 < NB; ++i2) {
    int b = tb + 16 * i2;
#pragma unroll
    for (int j = 0; j < NO; ++j) {
      int o = to + 16 * j;
      float r = acc[i2][j];
      float* dst = (o < HH || !outB) ? (outA + (nb + b) * HH + (o % HH))
                                     : (outB + (nb + b) * HH + (o - HH));
      if (accum) r += *dst;
      if (bp) {
        float ba = 0.f;
#pragma unroll
        for (int d = 0; d < DD; ++d) ba += esm[d] * fin(bp[d * O + o]);
        r += ba;
      }
      r = fin(r);
      if (act == 1) r = sigmoid_safe(r);
      else if (act == 2) r = tanh_safe(r);
      if (update) {
        float rg = rb[(nb + b) * HH + o];
        float hold = hio[(nb + b) * HH + o];
        hio[(nb + b) * HH + o] = rg * hold + (1.f - rg) * r;
      } else {
        *dst = r;
      }
    }
  }
}

// ---- out[(b0+bb), o, n] = sum_h h1[n,bb,h]*cw[o*H+h] + cb[o] ----
__global__ void kfin(const float* __restrict__ h1, const float* __restrict__ cw,
                     const float* __restrict__ cb, float* __restrict__ out,
                     int b0, int CB) {
  int idx = blockIdx.x * 256 + threadIdx.x;
  if (idx >= CB * TT * NN) return;
  int n = idx % NN;
  int o = (idx / NN) % TT;
  int bb = idx / (NN * TT);
  const float* hp = h1 + ((size_t)n * CB + bb) * HH;
  float acc = fin(cb[o]);
#pragma unroll
  for (int hh = 0; hh < HH; ++hh) acc += hp[hh] * fin(cw[o * HH + hh]);
  out[((size_t)(b0 + bb) * TT + o) * NN + n] = fin(acc);
}

template <int CB>
static void run_chunks(const float* src, const float* E,
                       const float* gwp0, const float* gbp0,
                       const float* uwp0, const float* ubp0,
                       const float* gwp1, const float* gbp1,
                       const float* uwp1, const float* ubp1,
                       const float* cw, const float* cb,
                       float* out, f16* Mh, f16* Ml,
                       char* wsp, size_t off0, hipStream_t stream) {
  size_t off = off0;
  auto allocf = [&](size_t nelem) {
    float* p = (float*)(wsp + off);
    off += (nelem * 4 + 255) & ~(size_t)255;
    return p;
  };
  auto alloch = [&](size_t nelem) {
    f16* p = (f16*)(wsp + off);
    off += (nelem * 2 + 255) & ~(size_t)255;
    return p;
  };
  const int C = CB * HH;
  const size_t NC = (size_t)NN * C;
  float* P1  = allocf(NC);
  float* P2  = allocf(NC);
  float* h0  = allocf(NC);
  float* h1  = allocf(NC);
  float* zb  = allocf(NC);
  float* rbf = allocf(NC);
  float* hc  = allocf(NC);
  f16* vh = alloch(NC);
  f16* vl = alloch(NC);
  float* xb0 = allocf((size_t)NN * CB);
  float* xb1 = allocf((size_t)NN * CB);
  float* xb2 = allocf((size_t)NN * CB);
  f16* xth = alloch((size_t)NN * CB);
  f16* xtl = alloch((size_t)NN * CB);

  const int EW = (int)((NC + 255) / 256);
  const int EWS = (NN * CB + 255) / 256;
  const dim3 gConv((NN + 31) / 32, (C + 31) / 32);
  const dim3 gConvX((NN + 31) / 32, (CB + 31) / 32);
  const dim3 gMM((MR + 127) / 128, (C + 63) / 64);
  const dim3 gMMX((MR + 127) / 128, (CB + 63) / 64);
  float* nul = nullptr;

  auto chain = [&](const float* V) {   // V [NN][C] -> P1 = A@V, P2 = (2A^2-I)@V
    kconvT<<<gConv, 256, 0, stream>>>(V, vh, vl, C);
    kmm<<<gMM, 256, 0, stream>>>(Mh, Ml, vh, vl, P1, P2, C);
  };

  for (int b0 = 0; b0 < BB; b0 += CB) {
    kzero<<<EW, 256, 0, stream>>>(h0, (int)NC);
    kzero<<<EW, 256, 0, stream>>>(h1, (int)NC);
    for (int t = 0; t < TT; ++t) {
      // ===== layer 0 (x = src slice, Cin=1, Ctot=65) =====
      kx<<<EWS, 256, 0, stream>>>(src, xb0, t, b0, CB);
      kconvT<<<gConvX, 256, 0, stream>>>(xb0, xth, xtl, CB);
      kmm<<<gMMX, 256, 0, stream>>>(Mh, Ml, xth, xtl, xb1, xb2, CB);
      chain(h0);
      kgc<128, CB><<<NN, 256, 0, stream>>>(h0, P1, P2, gwp0, 65, 1, 64, E, nullptr,
                                           0, 0, zb, rbf, 0, nul, nul);
      kgc<128, CB><<<NN, 256, 0, stream>>>(xb0, xb1, xb2, gwp0, 65, 0, 1, E, gbp0,
                                           1, 1, zb, rbf, 0, nul, nul);
      kgc<64, CB><<<NN, 256, 0, stream>>>(xb0, xb1, xb2, uwp0, 65, 0, 1, E, nullptr,
                                          0, 0, hc, nul, 0, nul, nul);
      kmulz<<<EW, 256, 0, stream>>>(zb, h0, (int)NC);
      chain(zb);
      kgc<64, CB><<<NN, 256, 0, stream>>>(zb, P1, P2, uwp0, 65, 1, 64, E, ubp0,
                                          2, 1, hc, nul, 1, rbf, h0);
      // ===== layer 1 (x = h0, Cin=64, Ctot=128) =====
      chain(h1);
      kgc<128, CB><<<NN, 256, 0, stream>>>(h1, P1, P2, gwp1, 128, 64, 64, E, nullptr,
                                           0, 0, zb, rbf, 0, nul, nul);
      chain(h0);
      kgc<128, CB><<<NN, 256, 0, stream>>>(h0, P1, P2, gwp1, 128, 0, 64, E, gbp1,
                                           1, 1, zb, rbf, 0, nul, nul);
      kgc<64, CB><<<NN, 256, 0, stream>>>(h0, P1, P2, uwp1, 128, 0, 64, E, nullptr,
                                          0, 0, hc, nul, 0, nul, nul);
      kmulz<<<EW, 256, 0, stream>>>(zb, h1, (int)NC);
      chain(zb);
      kgc<64, CB><<<NN, 256, 0, stream>>>(zb, P1, P2, uwp1, 128, 64, 64, E, ubp1,
                                          2, 1, hc, nul, 1, rbf, h1);
    }
    kfin<<<(CB * TT * NN + 255) / 256, 256, 0, stream>>>(h1, cw, cb, out, b0, CB);
  }
}

extern "C" void kernel_launch(void* const* d_in, const int* in_sizes, int n_in,
                              void* d_out, int out_size, void* d_ws, size_t ws_size,
                              hipStream_t stream) {
  const float* src  = (const float*)d_in[0];
  const float* E    = (const float*)d_in[1];
  const float* gwp0 = (const float*)d_in[2];
  const float* gbp0 = (const float*)d_in[3];
  const float* uwp0 = (const float*)d_in[4];
  const float* ubp0 = (const float*)d_in[5];
  const float* gwp1 = (const float*)d_in[6];
  const float* gbp1 = (const float*)d_in[7];
  const float* uwp1 = (const float*)d_in[8];
  const float* ubp1 = (const float*)d_in[9];
  const float* cw   = (const float*)d_in[10];
  const float* cb   = (const float*)d_in[11];
  float* out = (float*)d_out;
  (void)in_sizes; (void)n_in; (void)out_size;

  char* wsp = (char*)d_ws;
  size_t off = 0;
  f16* Mh = (f16*)(wsp + off); off += ((size_t)MR * NN * 2 + 255) & ~(size_t)255;
  f16* Ml = (f16*)(wsp + off); off += ((size_t)MR * NN * 2 + 255) & ~(size_t)255;
  size_t off0 = off;  // chunk area starts here (~32 MB static so far)
  // transient prologue buffers overlap the chunk area (dead before chunks start)
  float* A  = (float*)(wsp + off0);
  float* A2 = (float*)(wsp + off0 + (((size_t)NN * NN * 4 + 255) & ~(size_t)255));

  ka<<<NN, 256, 0, stream>>>(E, A);
  {
    dim3 g((NN + TM - 1) / TM, (NN + TM - 1) / TM);
    kg<<<g, 256, 0, stream>>>(A, A, A2, NN);
  }
  ksplitM<<<(MR * NN + 255) / 256, 256, 0, stream>>>(A, A2, Mh, Ml);

  // footprints (incl. 32MB static): CB=64 ~297MB, CB=32 ~165MB, CB=16 ~99MB
  if (ws_size >= (size_t)320 * 1000 * 1000) {
    run_chunks<64>(src, E, gwp0, gbp0, uwp0, ubp0, gwp1, gbp1, uwp1, ubp1,
                   cw, cb, out, Mh, Ml, wsp, off0, stream);
  } else if (ws_size >= (size_t)185 * 1000 * 1000) {
    run_chunks<32>(src, E, gwp0, gbp0, uwp0, ubp0, gwp1, gbp1, uwp1, ubp1,
                   cw, cb, out, Mh, Ml, wsp, off0, stream);
  } else {
    run_chunks<16>(src, E, gwp0, gbp0, uwp0, ubp0, gwp1, gbp1, uwp1, ubp1,
                   cw, cb, out, Mh, Ml, wsp, off0, stream);
  }
}

// Round 12
// 62486.053 us; speedup vs baseline: 2.0219x; 1.3309x over previous
//
#include <hip/hip_runtime.h>
#include <hip/hip_bf16.h>
#include <math.h>

#define NN 2000
#define DD 16
#define BB 64
#define TT 12
#define HH 64
#define MR 4000   // rows of stacked M = [A ; 2A^2 - I]
#define SCL 2048.0f
#define ISCL (1.0f / 2048.0f)

typedef _Float16 f16;
typedef __attribute__((ext_vector_type(8))) _Float16 frag8h;  // 8 f16 = 4 VGPRs
typedef __attribute__((ext_vector_type(4))) float floatx4;

__device__ inline float fin(float v) {
  return (v == v && v > -1e30f && v < 1e30f) ? v : 0.f;
}
__device__ inline float sigmoid_safe(float x) {
  float e = expf(-fabsf(x));
  float s = 1.f / (1.f + e);
  return x >= 0.f ? s : 1.f - s;
}
__device__ inline float tanh_safe(float x) {
  float e = expf(-2.f * fabsf(x));
  float r = (1.f - e) / (1.f + e);
  return x >= 0.f ? r : -r;
}
// split v = hi + lo/2048, hi/lo f16
__device__ inline void split16(float v, f16& hi, f16& lo) {
  hi = (f16)v;
  lo = (f16)((v - (float)hi) * SCL);
}
// async global->LDS 16B: lands at (wave-uniform) l + lane*16
__device__ inline void gll16(const void* g, void* l) {
  __builtin_amdgcn_global_load_lds((const __attribute__((address_space(1))) void*)g,
                                   (__attribute__((address_space(3))) void*)l, 16, 0, 0);
}

__global__ void kzero(float* p, int n) {
  int i = blockIdx.x * 256 + threadIdx.x;
  if (i < n) p[i] = 0.f;
}

// ---- A = softmax(relu(E E^T), axis=1); all f32 ----
__global__ __launch_bounds__(256) void ka(const float* __restrict__ E,
                                          float* __restrict__ A) {
  __shared__ float s[NN];
  __shared__ float red[256];
  int n = blockIdx.x;
  float en[DD];
#pragma unroll
  for (int d = 0; d < DD; ++d) en[d] = fin(E[n * DD + d]);
  float lmax = 0.f;
  for (int m = threadIdx.x; m < NN; m += 256) {
    float acc = 0.f;
#pragma unroll
    for (int d = 0; d < DD; ++d) acc += en[d] * fin(E[m * DD + d]);
    acc = fmaxf(acc, 0.f);
    s[m] = acc;
    lmax = fmaxf(lmax, acc);
  }
  red[threadIdx.x] = lmax;
  __syncthreads();
  for (int w = 128; w > 0; w >>= 1) {
    if (threadIdx.x < w) red[threadIdx.x] = fmaxf(red[threadIdx.x], red[threadIdx.x + w]);
    __syncthreads();
  }
  float mx = red[0];
  __syncthreads();
  float lsum = 0.f;
  for (int m = threadIdx.x; m < NN; m += 256) {
    float e = expf(s[m] - mx);
    s[m] = e;
    lsum += e;
  }
  red[threadIdx.x] = lsum;
  __syncthreads();
  for (int w = 128; w > 0; w >>= 1) {
    if (threadIdx.x < w) red[threadIdx.x] += red[threadIdx.x + w];
    __syncthreads();
  }
  float inv = 1.f / red[0];
  for (int m = threadIdx.x; m < NN; m += 256) A[(size_t)n * NN + m] = s[m] * inv;
}

// ---- C(NN x cols) = A @ V ; f32, 64x64 tile (prologue only, for A^2) ----
#define TM 64
#define TK 32
__global__ __launch_bounds__(256) void kg(const float* __restrict__ A,
                                          const float* __restrict__ V,
                                          float* __restrict__ C, int cols) {
  __shared__ float As[TK][TM + 1];
  __shared__ float Bs[TK][TM + 1];
  int r0 = blockIdx.x * TM;
  int c0 = blockIdx.y * TM;
  int tid = threadIdx.x;
  int tx = tid % 16;
  int ty = tid / 16;
  float acc[4][4];
#pragma unroll
  for (int i = 0; i < 4; ++i)
#pragma unroll
    for (int j = 0; j < 4; ++j) acc[i][j] = 0.f;
  for (int k0 = 0; k0 < NN; k0 += TK) {
    for (int i = tid; i < TM * TK; i += 256) {
      int rr = i / TK, kk = i % TK;
      int gr = r0 + rr, gk = k0 + kk;
      As[kk][rr] = (gr < NN && gk < NN) ? A[(size_t)gr * NN + gk] : 0.f;
    }
    for (int i = tid; i < TK * TM; i += 256) {
      int kk = i / TM, cc = i % TM;
      int gk = k0 + kk, gc = c0 + cc;
      Bs[kk][cc] = (gk < NN && gc < cols) ? V[(size_t)gk * cols + gc] : 0.f;
    }
    __syncthreads();
#pragma unroll 4
    for (int kk = 0; kk < TK; ++kk) {
      float a[4], b[4];
#pragma unroll
      for (int i = 0; i < 4; ++i) a[i] = As[kk][ty * 4 + i];
#pragma unroll
      for (int j = 0; j < 4; ++j) b[j] = Bs[kk][tx * 4 + j];
#pragma unroll
      for (int i = 0; i < 4; ++i)
#pragma unroll
        for (int j = 0; j < 4; ++j) acc[i][j] += a[i] * b[j];
    }
    __syncthreads();
  }
#pragma unroll
  for (int i = 0; i < 4; ++i) {
    int gr = r0 + ty * 4 + i;
    if (gr >= NN) continue;
#pragma unroll
    for (int j = 0; j < 4; ++j) {
      int gc = c0 + tx * 4 + j;
      if (gc < cols) C[(size_t)gr * cols + gc] = acc[i][j];
    }
  }
}

// ---- build split M = [A ; 2A^2 - I] as f16 hi + lo/2048 ----
__global__ void ksplitM(const float* __restrict__ A, const float* __restrict__ A2,
                        f16* __restrict__ Mh, f16* __restrict__ Ml) {
  int i = blockIdx.x * 256 + threadIdx.x;
  if (i >= MR * NN) return;
  int m = i / NN;
  int k = i % NN;
  float v;
  if (m < NN) v = A[(size_t)m * NN + k];
  else {
    int mm = m - NN;
    v = 2.f * A2[(size_t)mm * NN + k] - (mm == k ? 1.f : 0.f);
  }
  f16 hi, lo;
  split16(v, hi, lo);
  Mh[i] = hi;
  Ml[i] = lo;
}

// ---- split+transpose: V f32 [2000][cols] -> Th/Tl f16 [cols][2000] ----
__global__ __launch_bounds__(256) void kconvT(const float* __restrict__ V,
                                              f16* __restrict__ Th,
                                              f16* __restrict__ Tl, int cols) {
  __shared__ float sh[32][33];
  int k0 = blockIdx.x * 32;
  int c0 = blockIdx.y * 32;
  int tx = threadIdx.x % 32;
  int ty = threadIdx.x / 32;  // 0..7
#pragma unroll
  for (int i = 0; i < 4; ++i) {
    int r = k0 + ty + i * 8;
    int c = c0 + tx;
    sh[ty + i * 8][tx] = (r < NN && c < cols) ? V[(size_t)r * cols + c] : 0.f;
  }
  __syncthreads();
#pragma unroll
  for (int i = 0; i < 4; ++i) {
    int cc = c0 + ty + i * 8;
    int kk = k0 + tx;
    if (cc < cols && kk < NN) {
      f16 hi, lo;
      split16(sh[tx][ty + i * 8], hi, lo);
      Th[(size_t)cc * NN + kk] = hi;
      Tl[(size_t)cc * NN + kk] = lo;
    }
  }
}

// ---- MFMA GEMM v2: C = (Mh + Ml/2048) @ (Bh + Bl/2048), dropping Ml@Bl.
// 128x128 block tile, 4 waves (2x2), per-wave 64x64, dual f32 accumulators.
// Staging via global_load_lds (16B/lane). LDS tiles are unpadded 128x32 f16 with
// per-row k-chunk swizzle: row r stores logical chunk q at position (q+r)&3
// (breaks the 8-way bank conflict of the unpadded layout; <=4-way remains).
#define KT 32
__global__ __launch_bounds__(256, 2) void kmm(const f16* __restrict__ Mh,
                                              const f16* __restrict__ Ml,
                                              const f16* __restrict__ Bh,
                                              const f16* __restrict__ Bl,
                                              float* __restrict__ C1,
                                              float* __restrict__ C2, int cols) {
  __shared__ __align__(16) f16 Ash[128 * KT];
  __shared__ __align__(16) f16 Asl[128 * KT];
  __shared__ __align__(16) f16 Bsh[128 * KT];
  __shared__ __align__(16) f16 Bsl[128 * KT];
  int tid = threadIdx.x;
  int lane = tid & 63;
  int wave = tid >> 6;
  int wr = wave >> 1;   // 0..1
  int wc = wave & 1;    // 0..1
  int bx = blockIdx.x;
  int by = blockIdx.y;
  floatx4 acc0[4][4], acc1[4][4];
#pragma unroll
  for (int i = 0; i < 4; ++i)
#pragma unroll
    for (int j = 0; j < 4; ++j) {
      acc0[i][j] = (floatx4){0.f, 0.f, 0.f, 0.f};
      acc1[i][j] = (floatx4){0.f, 0.f, 0.f, 0.f};
    }
  const frag8h zf = {0, 0, 0, 0, 0, 0, 0, 0};
  const int q = lane >> 4;        // k-chunk index for frag reads
  const int pl = lane & 3;        // LDS chunk position this lane stages

  // compute fragment LDS offsets (swizzled)
  auto comp = [&]() {
    frag8h ah[4], al[4], bh[4], bl[4];
#pragma unroll
    for (int mi = 0; mi < 4; ++mi) {
      int row = wr * 64 + mi * 16 + (lane & 15);
      int pp = (q + row) & 3;
      ah[mi] = *(const frag8h*)(&Ash[row * KT + pp * 8]);
      al[mi] = *(const frag8h*)(&Asl[row * KT + pp * 8]);
    }
#pragma unroll
    for (int ni = 0; ni < 4; ++ni) {
      int col = wc * 64 + ni * 16 + (lane & 15);
      int pp = (q + col) & 3;
      bh[ni] = *(const frag8h*)(&Bsh[col * KT + pp * 8]);
      bl[ni] = *(const frag8h*)(&Bsl[col * KT + pp * 8]);
    }
#pragma unroll
    for (int mi = 0; mi < 4; ++mi)
#pragma unroll
      for (int ni = 0; ni < 4; ++ni) {
        acc0[mi][ni] = __builtin_amdgcn_mfma_f32_16x16x32_f16(ah[mi], bh[ni], acc0[mi][ni], 0, 0, 0);
        acc1[mi][ni] = __builtin_amdgcn_mfma_f32_16x16x32_f16(ah[mi], bl[ni], acc1[mi][ni], 0, 0, 0);
        acc1[mi][ni] = __builtin_amdgcn_mfma_f32_16x16x32_f16(al[mi], bh[ni], acc1[mi][ni], 0, 0, 0);
      }
  };

  // fast path: full 32-k tiles via global_load_lds
  for (int k0 = 0; k0 + KT <= NN; k0 += KT) {
#pragma unroll
    for (int jj = 0; jj < 2; ++jj) {
      int j = wave * 2 + jj;            // inst index 0..7, covers rows j*16..j*16+15
      int r = j * 16 + (lane >> 2);     // staged row (this lane)
      int qg = (pl - r) & 3;            // logical chunk that belongs at position pl
      size_t ko = (size_t)k0 + qg * 8;
      int gra = bx * 128 + r;
      if (gra < MR) {
        gll16(Mh + (size_t)gra * NN + ko, Ash + j * 512);
        gll16(Ml + (size_t)gra * NN + ko, Asl + j * 512);
      }
      int grb = by * 128 + r;
      if (grb < cols) {
        gll16(Bh + (size_t)grb * NN + ko, Bsh + j * 512);
        gll16(Bl + (size_t)grb * NN + ko, Bsl + j * 512);
      }
    }
    __syncthreads();
    comp();
    __syncthreads();
  }
  // tail (k0 = 1984, 16 valid k): guarded VGPR staging with swizzled placement
  {
    int k0 = (NN / KT) * KT;
    if (k0 < NN) {
      for (int c = tid; c < 512; c += 256) {
        int r = c >> 2, qc = c & 3;
        int pq = (qc + r) & 3;
        int gk = k0 + qc * 8;
        bool kok = (gk + 8 <= NN);
        int gra = bx * 128 + r;
        bool aok = kok && (gra < MR);
        size_t ga = (size_t)gra * NN + gk;
        *(frag8h*)(&Ash[r * KT + pq * 8]) = aok ? *(const frag8h*)(Mh + ga) : zf;
        *(frag8h*)(&Asl[r * KT + pq * 8]) = aok ? *(const frag8h*)(Ml + ga) : zf;
        int grb = by * 128 + r;
        bool bok = kok && (grb < cols);
        size_t gb = (size_t)grb * NN + gk;
        *(frag8h*)(&Bsh[r * KT + pq * 8]) = bok ? *(const frag8h*)(Bh + gb) : zf;
        *(frag8h*)(&Bsl[r * KT + pq * 8]) = bok ? *(const frag8h*)(Bl + gb) : zf;
      }
      __syncthreads();
      comp();
      __syncthreads();
    }
  }
  // store: C/D layout col = lane&15, row = (lane>>4)*4 + reg
#pragma unroll
  for (int mi = 0; mi < 4; ++mi) {
#pragma unroll
    for (int ni = 0; ni < 4; ++ni) {
#pragma unroll
      for (int reg = 0; reg < 4; ++reg) {
        int row = bx * 128 + wr * 64 + mi * 16 + (lane >> 4) * 4 + reg;
        int col = by * 128 + wc * 64 + ni * 16 + (lane & 15);
        if (col >= cols || row >= MR) continue;
        float v = acc0[mi][ni][reg] + acc1[mi][ni][reg] * ISCL;
        if (row < NN) C1[(size_t)row * cols + col] = v;
        else C2[(size_t)(row - NN) * cols + col] = v;
      }
    }
  }
}

// ---- xb[n*CB + bb] = src[((b0+bb)*TT + t)*NN + n] ----
__global__ void kx(const float* __restrict__ src, float* __restrict__ xb,
                   int t, int b0, int CB) {
  int i = blockIdx.x * 256 + threadIdx.x;
  if (i >= NN * CB) return;
  int bb = i % CB;
  int n = i / CB;
  xb[i] = fin(src[((size_t)(b0 + bb) * TT + t) * NN + n]);
}

// ---- zb[i] *= h[i] ----
__global__ void kmulz(float* __restrict__ zb, const float* __restrict__ h, int n) {
  int i = blockIdx.x * 256 + threadIdx.x;
  if (i < n) zb[i] = zb[i] * h[i];
}

// ---- gconv (unchanged from passing R9/R11) ----
template <int O, int CB>
__global__ __launch_bounds__(256) void kgc(
    const float* __restrict__ x0, const float* __restrict__ x1, const float* __restrict__ x2,
    const float* __restrict__ wp, int Ctot, int base_c, int nC,
    const float* __restrict__ E, const float* __restrict__ bp,
    int act, int accum, float* outA, float* outB,
    int update, const float* __restrict__ rb, float* hio) {
  __shared__ float xs[8][CB + 1];
  __shared__ float ws[8][O];
  __shared__ float esm[DD];
  int n = blockIdx.x;
  int tid = threadIdx.x;
  int to = tid % 16;
  int tb = tid / 16;
  if (tid < DD) esm[tid] = fin(E[n * DD + tid]);
  __syncthreads();
  constexpr int NO = O / 16;
  constexpr int NB = CB / 16;
  float acc[NB][NO];
#pragma unroll
  for (int i = 0; i < NB; ++i)
#pragma unroll
    for (int j = 0; j < NO; ++j) acc[i][j] = 0.f;
  const size_t nb = (size_t)n * CB;
  for (int k = 0; k < 3; ++k) {
    const float* xk = (k == 0) ? x0 : (k == 1) ? x1 : x2;
    for (int c0 = 0; c0 < nC; c0 += 8) {
      int chunk = (nC - c0 < 8) ? (nC - c0) : 8;
      for (int i = tid; i < chunk * CB; i += 256) {
        int cc = i % chunk;
        int b = i / chunk;
        xs[cc][b] = xk[(nb + b) * nC + c0 + cc];
      }
      for (int i = tid; i < chunk * O; i += 256) {
        int o = i % O;
        int cc = i / O;
        int crow = base_c + c0 + cc;
        float wa = 0.f;
#pragma unroll
        for (int d = 0; d < DD; ++d)
          wa += esm[d] * fin(wp[((size_t)(d * 3 + k) * Ctot + crow) * O + o]);
        ws[cc][o] = wa;
      }
      __syncthreads();
      for (int cc = 0; cc < chunk; ++cc) {
        float xv[NB];
#pragma unroll
        for (int i = 0; i < NB; ++i) xv[i] = xs[cc][tb + 16 * i];
#pragma unroll
        for (int j = 0; j < NO; ++j) {
          float wv = ws[cc][to + 16 * j];
#pragma unroll
          for (int i = 0; i < NB; ++i) acc[i][j] += xv[i] * wv;
        }
      }
      __syncthreads();
    }
  }
#pragma unroll
  for (int i2 = 0; i2 < NB; ++i2) {
    int b = tb + 16 * i2;
#pragma unroll
    for (int j = 0; j < NO; ++j) {
      int o = to + 16 * j;
      float r = acc[i2][j];
      float* dst = (o < HH || !outB) ? (outA + (nb + b) * HH + (o % HH))
                                     : (outB + (nb + b) * HH + (o - HH));
      if (accum) r += *dst;
      if (bp) {
        float ba = 0.f;
#pragma unroll
        for (int d = 0; d < DD; ++d) ba += esm[d] * fin(bp[d * O + o]);
        r += ba;
      }
      r = fin(r);
      if (act == 1) r = sigmoid_safe(r);
      else if (act == 2) r = tanh_safe(r);
      if (update) {
        float rg = rb[(nb + b) * HH + o];
        float hold = hio[(nb + b) * HH + o];
        hio[(nb + b) * HH + o] = rg * hold + (1.f - rg) * r;
      } else {
        *dst = r;
      }
    }
  }
}

// ---- out[(b0+bb), o, n] = sum_h h1[n,bb,h]*cw[o*H+h] + cb[o] ----
__global__ void kfin(const float* __restrict__ h1, const float* __restrict__ cw,
                     const float* __restrict__ cb, float* __restrict__ out,
                     int b0, int CB) {
  int idx = blockIdx.x * 256 + threadIdx.x;
  if (idx >= CB * TT * NN) return;
  int n = idx % NN;
  int o = (idx / NN) % TT;
  int bb = idx / (NN * TT);
  const float* hp = h1 + ((size_t)n * CB + bb) * HH;
  float acc = fin(cb[o]);
#pragma unroll
  for (int hh = 0; hh < HH; ++hh) acc += hp[hh] * fin(cw[o * HH + hh]);
  out[((size_t)(b0 + bb) * TT + o) * NN + n] = fin(acc);
}

template <int CB>
static void run_chunks(const float* src, const float* E,
                       const float* gwp0, const float* gbp0,
                       const float* uwp0, const float* ubp0,
                       const float* gwp1, const float* gbp1,
                       const float* uwp1, const float* ubp1,
                       const float* cw, const float* cb,
                       float* out, f16* Mh, f16* Ml,
                       char* wsp, size_t off0, hipStream_t stream) {
  size_t off = off0;
  auto allocf = [&](size_t nelem) {
    float* p = (float*)(wsp + off);
    off += (nelem * 4 + 255) & ~(size_t)255;
    return p;
  };
  auto alloch = [&](size_t nelem) {
    f16* p = (f16*)(wsp + off);
    off += (nelem * 2 + 255) & ~(size_t)255;
    return p;
  };
  const int C = CB * HH;
  const size_t NC = (size_t)NN * C;
  float* P1  = allocf(NC);
  float* P2  = allocf(NC);
  float* h0  = allocf(NC);
  float* h1  = allocf(NC);
  float* zb  = allocf(NC);
  float* rbf = allocf(NC);
  float* hc  = allocf(NC);
  f16* vh = alloch(NC);
  f16* vl = alloch(NC);
  float* xb0 = allocf((size_t)NN * CB);
  float* xb1 = allocf((size_t)NN * CB);
  float* xb2 = allocf((size_t)NN * CB);
  f16* xth = alloch((size_t)NN * CB);
  f16* xtl = alloch((size_t)NN * CB);

  const int EW = (int)((NC + 255) / 256);
  const int EWS = (NN * CB + 255) / 256;
  const dim3 gConv((NN + 31) / 32, (C + 31) / 32);
  const dim3 gConvX((NN + 31) / 32, (CB + 31) / 32);
  const dim3 gMM((MR + 127) / 128, (C + 127) / 128);
  const dim3 gMMX((MR + 127) / 128, (CB + 127) / 128);
  float* nul = nullptr;

  auto chain = [&](const float* V) {   // V [NN][C] -> P1 = A@V, P2 = (2A^2-I)@V
    kconvT<<<gConv, 256, 0, stream>>>(V, vh, vl, C);
    kmm<<<gMM, 256, 0, stream>>>(Mh, Ml, vh, vl, P1, P2, C);
  };

  for (int b0 = 0; b0 < BB; b0 += CB) {
    kzero<<<EW, 256, 0, stream>>>(h0, (int)NC);
    kzero<<<EW, 256, 0, stream>>>(h1, (int)NC);
    for (int t = 0; t < TT; ++t) {
      // ===== layer 0 (x = src slice, Cin=1, Ctot=65) =====
      kx<<<EWS, 256, 0, stream>>>(src, xb0, t, b0, CB);
      kconvT<<<gConvX, 256, 0, stream>>>(xb0, xth, xtl, CB);
      kmm<<<gMMX, 256, 0, stream>>>(Mh, Ml, xth, xtl, xb1, xb2, CB);
      chain(h0);
      kgc<128, CB><<<NN, 256, 0, stream>>>(h0, P1, P2, gwp0, 65, 1, 64, E, nullptr,
                                           0, 0, zb, rbf, 0, nul, nul);
      kgc<128, CB><<<NN, 256, 0, stream>>>(xb0, xb1, xb2, gwp0, 65, 0, 1, E, gbp0,
                                           1, 1, zb, rbf, 0, nul, nul);
      kgc<64, CB><<<NN, 256, 0, stream>>>(xb0, xb1, xb2, uwp0, 65, 0, 1, E, nullptr,
                                          0, 0, hc, nul, 0, nul, nul);
      kmulz<<<EW, 256, 0, stream>>>(zb, h0, (int)NC);
      chain(zb);
      kgc<64, CB><<<NN, 256, 0, stream>>>(zb, P1, P2, uwp0, 65, 1, 64, E, ubp0,
                                          2, 1, hc, nul, 1, rbf, h0);
      // ===== layer 1 (x = h0, Cin=64, Ctot=128) =====
      chain(h1);
      kgc<128, CB><<<NN, 256, 0, stream>>>(h1, P1, P2, gwp1, 128, 64, 64, E, nullptr,
                                           0, 0, zb, rbf, 0, nul, nul);
      chain(h0);
      kgc<128, CB><<<NN, 256, 0, stream>>>(h0, P1, P2, gwp1, 128, 0, 64, E, gbp1,
                                           1, 1, zb, rbf, 0, nul, nul);
      kgc<64, CB><<<NN, 256, 0, stream>>>(h0, P1, P2, uwp1, 128, 0, 64, E, nullptr,
                                          0, 0, hc, nul, 0, nul, nul);
      kmulz<<<EW, 256, 0, stream>>>(zb, h1, (int)NC);
      chain(zb);
      kgc<64, CB><<<NN, 256, 0, stream>>>(zb, P1, P2, uwp1, 128, 64, 64, E, ubp1,
                                          2, 1, hc, nul, 1, rbf, h1);
    }
    kfin<<<(CB * TT * NN + 255) / 256, 256, 0, stream>>>(h1, cw, cb, out, b0, CB);
  }
}

extern "C" void kernel_launch(void* const* d_in, const int* in_sizes, int n_in,
                              void* d_out, int out_size, void* d_ws, size_t ws_size,
                              hipStream_t stream) {
  const float* src  = (const float*)d_in[0];
  const float* E    = (const float*)d_in[1];
  const float* gwp0 = (const float*)d_in[2];
  const float* gbp0 = (const float*)d_in[3];
  const float* uwp0 = (const float*)d_in[4];
  const float* ubp0 = (const float*)d_in[5];
  const float* gwp1 = (const float*)d_in[6];
  const float* gbp1 = (const float*)d_in[7];
  const float* uwp1 = (const float*)d_in[8];
  const float* ubp1 = (const float*)d_in[9];
  const float* cw   = (const float*)d_in[10];
  const float* cb   = (const float*)d_in[11];
  float* out = (float*)d_out;
  (void)in_sizes; (void)n_in; (void)out_size;

  char* wsp = (char*)d_ws;
  size_t off = 0;
  f16* Mh = (f16*)(wsp + off); off += ((size_t)MR * NN * 2 + 255) & ~(size_t)255;
  f16* Ml = (f16*)(wsp + off); off += ((size_t)MR * NN * 2 + 255) & ~(size_t)255;
  size_t off0 = off;  // chunk area starts here (~32 MB static so far)
  // transient prologue buffers overlap the chunk area (dead before chunks start)
  float* A  = (float*)(wsp + off0);
  float* A2 = (float*)(wsp + off0 + (((size_t)NN * NN * 4 + 255) & ~(size_t)255));

  ka<<<NN, 256, 0, stream>>>(E, A);
  {
    dim3 g((NN + TM - 1) / TM, (NN + TM - 1) / TM);
    kg<<<g, 256, 0, stream>>>(A, A, A2, NN);
  }
  ksplitM<<<(MR * NN + 255) / 256, 256, 0, stream>>>(A, A2, Mh, Ml);

  // footprints (incl. 32MB static): CB=64 ~297MB, CB=32 ~165MB, CB=16 ~99MB
  if (ws_size >= (size_t)320 * 1000 * 1000) {
    run_chunks<64>(src, E, gwp0, gbp0, uwp0, ubp0, gwp1, gbp1, uwp1, ubp1,
                   cw, cb, out, Mh, Ml, wsp, off0, stream);
  } else if (ws_size >= (size_t)185 * 1000 * 1000) {
    run_chunks<32>(src, E, gwp0, gbp0, uwp0, ubp0, gwp1, gbp1, uwp1, ubp1,
                   cw, cb, out, Mh, Ml, wsp, off0, stream);
  } else {
    run_chunks<16>(src, E, gwp0, gbp0, uwp0, ubp0, gwp1, gbp1, uwp1, ubp1,
                   cw, cb, out, Mh, Ml, wsp, off0, stream);
  }
}

// Round 13
// 61844.812 us; speedup vs baseline: 2.0429x; 1.0104x over previous
//
#include <hip/hip_runtime.h>
#include <hip/hip_bf16.h>
#include <math.h>

#define NN 2000
#define DD 16
#define BB 64
#define TT 12
#define HH 64
#define MR 4000   // rows of stacked M = [A ; 2A^2 - I]
#define SCL 2048.0f
#define ISCL (1.0f / 2048.0f)

typedef _Float16 f16;
typedef __attribute__((ext_vector_type(8))) _Float16 frag8h;  // 8 f16 = 4 VGPRs
typedef __attribute__((ext_vector_type(4))) float floatx4;

__device__ inline float fin(float v) {
  return (v == v && v > -1e30f && v < 1e30f) ? v : 0.f;
}
__device__ inline float sigmoid_safe(float x) {
  float e = expf(-fabsf(x));
  float s = 1.f / (1.f + e);
  return x >= 0.f ? s : 1.f - s;
}
__device__ inline float tanh_safe(float x) {
  float e = expf(-2.f * fabsf(x));
  float r = (1.f - e) / (1.f + e);
  return x >= 0.f ? r : -r;
}
// split v = hi + lo/2048, hi/lo f16
__device__ inline void split16(float v, f16& hi, f16& lo) {
  hi = (f16)v;
  lo = (f16)((v - (float)hi) * SCL);
}
// async global->LDS 16B: lands at (wave-uniform) l + lane*16
__device__ inline void gll16(const void* g, void* l) {
  __builtin_amdgcn_global_load_lds((const __attribute__((address_space(1))) void*)g,
                                   (__attribute__((address_space(3))) void*)l, 16, 0, 0);
}

__global__ void kzero(float* p, int n) {
  int i = blockIdx.x * 256 + threadIdx.x;
  if (i < n) p[i] = 0.f;
}

// ---- A = softmax(relu(E E^T), axis=1); all f32 ----
__global__ __launch_bounds__(256) void ka(const float* __restrict__ E,
                                          float* __restrict__ A) {
  __shared__ float s[NN];
  __shared__ float red[256];
  int n = blockIdx.x;
  float en[DD];
#pragma unroll
  for (int d = 0; d < DD; ++d) en[d] = fin(E[n * DD + d]);
  float lmax = 0.f;
  for (int m = threadIdx.x; m < NN; m += 256) {
    float acc = 0.f;
#pragma unroll
    for (int d = 0; d < DD; ++d) acc += en[d] * fin(E[m * DD + d]);
    acc = fmaxf(acc, 0.f);
    s[m] = acc;
    lmax = fmaxf(lmax, acc);
  }
  red[threadIdx.x] = lmax;
  __syncthreads();
  for (int w = 128; w > 0; w >>= 1) {
    if (threadIdx.x < w) red[threadIdx.x] = fmaxf(red[threadIdx.x], red[threadIdx.x + w]);
    __syncthreads();
  }
  float mx = red[0];
  __syncthreads();
  float lsum = 0.f;
  for (int m = threadIdx.x; m < NN; m += 256) {
    float e = expf(s[m] - mx);
    s[m] = e;
    lsum += e;
  }
  red[threadIdx.x] = lsum;
  __syncthreads();
  for (int w = 128; w > 0; w >>= 1) {
    if (threadIdx.x < w) red[threadIdx.x] += red[threadIdx.x + w];
    __syncthreads();
  }
  float inv = 1.f / red[0];
  for (int m = threadIdx.x; m < NN; m += 256) A[(size_t)n * NN + m] = s[m] * inv;
}

// ---- C(NN x cols) = A @ V ; f32, 64x64 tile (prologue only, for A^2) ----
#define TM 64
#define TK 32
__global__ __launch_bounds__(256) void kg(const float* __restrict__ A,
                                          const float* __restrict__ V,
                                          float* __restrict__ C, int cols) {
  __shared__ float As[TK][TM + 1];
  __shared__ float Bs[TK][TM + 1];
  int r0 = blockIdx.x * TM;
  int c0 = blockIdx.y * TM;
  int tid = threadIdx.x;
  int tx = tid % 16;
  int ty = tid / 16;
  float acc[4][4];
#pragma unroll
  for (int i = 0; i < 4; ++i)
#pragma unroll
    for (int j = 0; j < 4; ++j) acc[i][j] = 0.f;
  for (int k0 = 0; k0 < NN; k0 += TK) {
    for (int i = tid; i < TM * TK; i += 256) {
      int rr = i / TK, kk = i % TK;
      int gr = r0 + rr, gk = k0 + kk;
      As[kk][rr] = (gr < NN && gk < NN) ? A[(size_t)gr * NN + gk] : 0.f;
    }
    for (int i = tid; i < TK * TM; i += 256) {
      int kk = i / TM, cc = i % TM;
      int gk = k0 + kk, gc = c0 + cc;
      Bs[kk][cc] = (gk < NN && gc < cols) ? V[(size_t)gk * cols + gc] : 0.f;
    }
    __syncthreads();
#pragma unroll 4
    for (int kk = 0; kk < TK; ++kk) {
      float a[4], b[4];
#pragma unroll
      for (int i = 0; i < 4; ++i) a[i] = As[kk][ty * 4 + i];
#pragma unroll
      for (int j = 0; j < 4; ++j) b[j] = Bs[kk][tx * 4 + j];
#pragma unroll
      for (int i = 0; i < 4; ++i)
#pragma unroll
        for (int j = 0; j < 4; ++j) acc[i][j] += a[i] * b[j];
    }
    __syncthreads();
  }
#pragma unroll
  for (int i = 0; i < 4; ++i) {
    int gr = r0 + ty * 4 + i;
    if (gr >= NN) continue;
#pragma unroll
    for (int j = 0; j < 4; ++j) {
      int gc = c0 + tx * 4 + j;
      if (gc < cols) C[(size_t)gr * cols + gc] = acc[i][j];
    }
  }
}

// ---- build split M = [A ; 2A^2 - I] as f16 hi + lo/2048 ----
__global__ void ksplitM(const float* __restrict__ A, const float* __restrict__ A2,
                        f16* __restrict__ Mh, f16* __restrict__ Ml) {
  int i = blockIdx.x * 256 + threadIdx.x;
  if (i >= MR * NN) return;
  int m = i / NN;
  int k = i % NN;
  float v;
  if (m < NN) v = A[(size_t)m * NN + k];
  else {
    int mm = m - NN;
    v = 2.f * A2[(size_t)mm * NN + k] - (mm == k ? 1.f : 0.f);
  }
  f16 hi, lo;
  split16(v, hi, lo);
  Mh[i] = hi;
  Ml[i] = lo;
}

// ---- split+transpose: V f32 [2000][cols] -> Th/Tl f16 [cols][2000] ----
__global__ __launch_bounds__(256) void kconvT(const float* __restrict__ V,
                                              f16* __restrict__ Th,
                                              f16* __restrict__ Tl, int cols) {
  __shared__ float sh[32][33];
  int k0 = blockIdx.x * 32;
  int c0 = blockIdx.y * 32;
  int tx = threadIdx.x % 32;
  int ty = threadIdx.x / 32;  // 0..7
#pragma unroll
  for (int i = 0; i < 4; ++i) {
    int r = k0 + ty + i * 8;
    int c = c0 + tx;
    sh[ty + i * 8][tx] = (r < NN && c < cols) ? V[(size_t)r * cols + c] : 0.f;
  }
  __syncthreads();
#pragma unroll
  for (int i = 0; i < 4; ++i) {
    int cc = c0 + ty + i * 8;
    int kk = k0 + tx;
    if (cc < cols && kk < NN) {
      f16 hi, lo;
      split16(sh[tx][ty + i * 8], hi, lo);
      Th[(size_t)cc * NN + kk] = hi;
      Tl[(size_t)cc * NN + kk] = lo;
    }
  }
}

// ---- MFMA GEMM v3: C = (Mh + Ml/2048) @ (Bh + Bl/2048), dropping Ml@Bl.
// 128x128 block tile, 4 waves (2x2), per-wave 64x64, dual f32 accumulators.
// LDS layout = chunk-major slots: each 1024B region j covers rows j*16..j*16+15;
// slot s = q*16 + r holds (row r, k-chunk q). Staged by global_load_lds where
// lane l supplies global addr of (row j*16+(l&15), chunk l>>4) -> LDS base+l*16.
// Fragment reads are then region_base + lane*16 (identity, conflict-minimal).
#define KT 32
__global__ __launch_bounds__(256, 2) void kmm(const f16* __restrict__ Mh,
                                              const f16* __restrict__ Ml,
                                              const f16* __restrict__ Bh,
                                              const f16* __restrict__ Bl,
                                              float* __restrict__ C1,
                                              float* __restrict__ C2, int cols) {
  __shared__ __align__(16) f16 Ash[128 * KT];
  __shared__ __align__(16) f16 Asl[128 * KT];
  __shared__ __align__(16) f16 Bsh[128 * KT];
  __shared__ __align__(16) f16 Bsl[128 * KT];
  int tid = threadIdx.x;
  int lane = tid & 63;
  int wave = tid >> 6;
  int wr = wave >> 1;   // 0..1
  int wc = wave & 1;    // 0..1
  int bx = blockIdx.x;
  int by = blockIdx.y;
  floatx4 acc0[4][4], acc1[4][4];
#pragma unroll
  for (int i = 0; i < 4; ++i)
#pragma unroll
    for (int j = 0; j < 4; ++j) {
      acc0[i][j] = (floatx4){0.f, 0.f, 0.f, 0.f};
      acc1[i][j] = (floatx4){0.f, 0.f, 0.f, 0.f};
    }
  const frag8h zf = {0, 0, 0, 0, 0, 0, 0, 0};

  auto comp = [&]() {
    frag8h ah[4], al[4], bh[4], bl[4];
#pragma unroll
    for (int mi = 0; mi < 4; ++mi) {
      int jr = wr * 4 + mi;                       // region index (16 rows each)
      ah[mi] = *(const frag8h*)(&Ash[jr * 512 + lane * 8]);
      al[mi] = *(const frag8h*)(&Asl[jr * 512 + lane * 8]);
    }
#pragma unroll
    for (int ni = 0; ni < 4; ++ni) {
      int jc = wc * 4 + ni;
      bh[ni] = *(const frag8h*)(&Bsh[jc * 512 + lane * 8]);
      bl[ni] = *(const frag8h*)(&Bsl[jc * 512 + lane * 8]);
    }
#pragma unroll
    for (int mi = 0; mi < 4; ++mi)
#pragma unroll
      for (int ni = 0; ni < 4; ++ni) {
        acc0[mi][ni] = __builtin_amdgcn_mfma_f32_16x16x32_f16(ah[mi], bh[ni], acc0[mi][ni], 0, 0, 0);
        acc1[mi][ni] = __builtin_amdgcn_mfma_f32_16x16x32_f16(ah[mi], bl[ni], acc1[mi][ni], 0, 0, 0);
        acc1[mi][ni] = __builtin_amdgcn_mfma_f32_16x16x32_f16(al[mi], bh[ni], acc1[mi][ni], 0, 0, 0);
      }
  };

  const int lr = lane & 15;   // row within region this lane stages
  const int lq = lane >> 4;   // k-chunk this lane stages
  // fast path: full 32-k tiles via global_load_lds
  for (int k0 = 0; k0 + KT <= NN; k0 += KT) {
#pragma unroll
    for (int jj = 0; jj < 2; ++jj) {
      int j = wave * 2 + jj;            // region 0..7
      int r = j * 16 + lr;
      size_t ko = (size_t)k0 + lq * 8;
      int gra = bx * 128 + r;
      if (gra < MR) {
        gll16(Mh + (size_t)gra * NN + ko, Ash + j * 512);
        gll16(Ml + (size_t)gra * NN + ko, Asl + j * 512);
      }
      int grb = by * 128 + r;
      if (grb < cols) {
        gll16(Bh + (size_t)grb * NN + ko, Bsh + j * 512);
        gll16(Bl + (size_t)grb * NN + ko, Bsl + j * 512);
      }
    }
    __syncthreads();
    comp();
    __syncthreads();
  }
  // tail (k0 = 1984, 16 valid k): guarded VGPR staging, same slot layout
  {
    int k0 = (NN / KT) * KT;
    if (k0 < NN) {
      for (int c = tid; c < 512; c += 256) {
        int j = c >> 6;          // region
        int ll = c & 63;         // slot within region
        int q = ll >> 4;
        int rr = ll & 15;
        int r = j * 16 + rr;
        int gk = k0 + q * 8;
        bool kok = (gk + 8 <= NN);
        int gra = bx * 128 + r;
        bool aok = kok && (gra < MR);
        size_t ga = (size_t)gra * NN + gk;
        *(frag8h*)(&Ash[c * 8]) = aok ? *(const frag8h*)(Mh + ga) : zf;
        *(frag8h*)(&Asl[c * 8]) = aok ? *(const frag8h*)(Ml + ga) : zf;
        int grb = by * 128 + r;
        bool bok = kok && (grb < cols);
        size_t gb = (size_t)grb * NN + gk;
        *(frag8h*)(&Bsh[c * 8]) = bok ? *(const frag8h*)(Bh + gb) : zf;
        *(frag8h*)(&Bsl[c * 8]) = bok ? *(const frag8h*)(Bl + gb) : zf;
      }
      __syncthreads();
      comp();
      __syncthreads();
    }
  }
  // store: C/D layout col = lane&15, row = (lane>>4)*4 + reg
#pragma unroll
  for (int mi = 0; mi < 4; ++mi) {
#pragma unroll
    for (int ni = 0; ni < 4; ++ni) {
#pragma unroll
      for (int reg = 0; reg < 4; ++reg) {
        int row = bx * 128 + wr * 64 + mi * 16 + (lane >> 4) * 4 + reg;
        int col = by * 128 + wc * 64 + ni * 16 + (lane & 15);
        if (col >= cols || row >= MR) continue;
        float v = acc0[mi][ni][reg] + acc1[mi][ni][reg] * ISCL;
        if (row < NN) C1[(size_t)row * cols + col] = v;
        else C2[(size_t)(row - NN) * cols + col] = v;
      }
    }
  }
}

// ---- xb[n*CB + bb] = src[((b0+bb)*TT + t)*NN + n] ----
__global__ void kx(const float* __restrict__ src, float* __restrict__ xb,
                   int t, int b0, int CB) {
  int i = blockIdx.x * 256 + threadIdx.x;
  if (i >= NN * CB) return;
  int bb = i % CB;
  int n = i / CB;
  xb[i] = fin(src[((size_t)(b0 + bb) * TT + t) * NN + n]);
}

// ---- zb[i] *= h[i] ----
__global__ void kmulz(float* __restrict__ zb, const float* __restrict__ h, int n) {
  int i = blockIdx.x * 256 + threadIdx.x;
  if (i < n) zb[i] = zb[i] * h[i];
}

// ---- gconv (unchanged from passing R9/R11/R12) ----
template <int O, int CB>
__global__ __launch_bounds__(256) void kgc(
    const float* __restrict__ x0, const float* __restrict__ x1, const float* __restrict__ x2,
    const float* __restrict__ wp, int Ctot, int base_c, int nC,
    const float* __restrict__ E, const float* __restrict__ bp,
    int act, int accum, float* outA, float* outB,
    int update, const float* __restrict__ rb, float* hio) {
  __shared__ float xs[8][CB + 1];
  __shared__ float ws[8][O];
  __shared__ float esm[DD];
  int n = blockIdx.x;
  int tid = threadIdx.x;
  int to = tid % 16;
  int tb = tid / 16;
  if (tid < DD) esm[tid] = fin(E[n * DD + tid]);
  __syncthreads();
  constexpr int NO = O / 16;
  constexpr int NB = CB / 16;
  float acc[NB][NO];
#pragma unroll
  for (int i = 0; i < NB; ++i)
#pragma unroll
    for (int j = 0; j < NO; ++j) acc[i][j] = 0.f;
  const size_t nb = (size_t)n * CB;
  for (int k = 0; k < 3; ++k) {
    const float* xk = (k == 0) ? x0 : (k == 1) ? x1 : x2;
    for (int c0 = 0; c0 < nC; c0 += 8) {
      int chunk = (nC - c0 < 8) ? (nC - c0) : 8;
      for (int i = tid; i < chunk * CB; i += 256) {
        int cc = i % chunk;
        int b = i / chunk;
        xs[cc][b] = xk[(nb + b) * nC + c0 + cc];
      }
      for (int i = tid; i < chunk * O; i += 256) {
        int o = i % O;
        int cc = i / O;
        int crow = base_c + c0 + cc;
        float wa = 0.f;
#pragma unroll
        for (int d = 0; d < DD; ++d)
          wa += esm[d] * fin(wp[((size_t)(d * 3 + k) * Ctot + crow) * O + o]);
        ws[cc][o] = wa;
      }
      __syncthreads();
      for (int cc = 0; cc < chunk; ++cc) {
        float xv[NB];
#pragma unroll
        for (int i = 0; i < NB; ++i) xv[i] = xs[cc][tb + 16 * i];
#pragma unroll
        for (int j = 0; j < NO; ++j) {
          float wv = ws[cc][to + 16 * j];
#pragma unroll
          for (int i = 0; i < NB; ++i) acc[i][j] += xv[i] * wv;
        }
      }
      __syncthreads();
    }
  }
#pragma unroll
  for (int i2 = 0; i2 < NB; ++i2) {
    int b = tb + 16 * i2;
#pragma unroll
    for (int j = 0; j < NO; ++j) {
      int o = to + 16 * j;
      float r = acc[i2][j];
      float* dst = (o < HH || !outB) ? (outA + (nb + b) * HH + (o % HH))
                                     : (outB + (nb + b) * HH + (o - HH));
      if (accum) r += *dst;
      if (bp) {
        float ba = 0.f;
#pragma unroll
        for (int d = 0; d < DD; ++d) ba += esm[d] * fin(bp[d * O + o]);
        r += ba;
      }
      r = fin(r);
      if (act == 1) r = sigmoid_safe(r);
      else if (act == 2) r = tanh_safe(r);
      if (update) {
        float rg = rb[(nb + b) * HH + o];
        float hold = hio[(nb + b) * HH + o];
        hio[(nb + b) * HH + o] = rg * hold + (1.f - rg) * r;
      } else {
        *dst = r;
      }
    }
  }
}

// ---- out[(b0+bb), o, n] = sum_h h1[n,bb,h]*cw[o*H+h] + cb[o] ----
__global__ void kfin(const float* __restrict__ h1, const float* __restrict__ cw,
                     const float* __restrict__ cb, float* __restrict__ out,
                     int b0, int CB) {
  int idx = blockIdx.x * 256 + threadIdx.x;
  if (idx >= CB * TT * NN) return;
  int n = idx % NN;
  int o = (idx / NN) % TT;
  int bb = idx / (NN * TT);
  const float* hp = h1 + ((size_t)n * CB + bb) * HH;
  float acc = fin(cb[o]);
#pragma unroll
  for (int hh = 0; hh < HH; ++hh) acc += hp[hh] * fin(cw[o * HH + hh]);
  out[((size_t)(b0 + bb) * TT + o) * NN + n] = fin(acc);
}

template <int CB>
static void run_chunks(const float* src, const float* E,
                       const float* gwp0, const float* gbp0,
                       const float* uwp0, const float* ubp0,
                       const float* gwp1, const float* gbp1,
                       const float* uwp1, const float* ubp1,
                       const float* cw, const float* cb,
                       float* out, f16* Mh, f16* Ml,
                       char* wsp, size_t off0, hipStream_t stream) {
  size_t off = off0;
  auto allocf = [&](size_t nelem) {
    float* p = (float*)(wsp + off);
    off += (nelem * 4 + 255) & ~(size_t)255;
    return p;
  };
  auto alloch = [&](size_t nelem) {
    f16* p = (f16*)(wsp + off);
    off += (nelem * 2 + 255) & ~(size_t)255;
    return p;
  };
  const int C = CB * HH;
  const size_t NC = (size_t)NN * C;
  float* P1  = allocf(NC);
  float* P2  = allocf(NC);
  float* h0  = allocf(NC);
  float* h1  = allocf(NC);
  float* zb  = allocf(NC);
  float* rbf = allocf(NC);
  float* hc  = allocf(NC);
  f16* vh = alloch(NC);
  f16* vl = alloch(NC);
  float* xb0 = allocf((size_t)NN * CB);
  float* xb1 = allocf((size_t)NN * CB);
  float* xb2 = allocf((size_t)NN * CB);
  f16* xth = alloch((size_t)NN * CB);
  f16* xtl = alloch((size_t)NN * CB);

  const int EW = (int)((NC + 255) / 256);
  const int EWS = (NN * CB + 255) / 256;
  const dim3 gConv((NN + 31) / 32, (C + 31) / 32);
  const dim3 gConvX((NN + 31) / 32, (CB + 31) / 32);
  const dim3 gMM((MR + 127) / 128, (C + 127) / 128);
  const dim3 gMMX((MR + 127) / 128, (CB + 127) / 128);
  float* nul = nullptr;

  auto chain = [&](const float* V) {   // V [NN][C] -> P1 = A@V, P2 = (2A^2-I)@V
    kconvT<<<gConv, 256, 0, stream>>>(V, vh, vl, C);
    kmm<<<gMM, 256, 0, stream>>>(Mh, Ml, vh, vl, P1, P2, C);
  };

  for (int b0 = 0; b0 < BB; b0 += CB) {
    kzero<<<EW, 256, 0, stream>>>(h0, (int)NC);
    kzero<<<EW, 256, 0, stream>>>(h1, (int)NC);
    for (int t = 0; t < TT; ++t) {
      // ===== layer 0 (x = src slice, Cin=1, Ctot=65) =====
      kx<<<EWS, 256, 0, stream>>>(src, xb0, t, b0, CB);
      kconvT<<<gConvX, 256, 0, stream>>>(xb0, xth, xtl, CB);
      kmm<<<gMMX, 256, 0, stream>>>(Mh, Ml, xth, xtl, xb1, xb2, CB);
      chain(h0);
      kgc<128, CB><<<NN, 256, 0, stream>>>(h0, P1, P2, gwp0, 65, 1, 64, E, nullptr,
                                           0, 0, zb, rbf, 0, nul, nul);
      kgc<128, CB><<<NN, 256, 0, stream>>>(xb0, xb1, xb2, gwp0, 65, 0, 1, E, gbp0,
                                           1, 1, zb, rbf, 0, nul, nul);
      kgc<64, CB><<<NN, 256, 0, stream>>>(xb0, xb1, xb2, uwp0, 65, 0, 1, E, nullptr,
                                          0, 0, hc, nul, 0, nul, nul);
      kmulz<<<EW, 256, 0, stream>>>(zb, h0, (int)NC);
      chain(zb);
      kgc<64, CB><<<NN, 256, 0, stream>>>(zb, P1, P2, uwp0, 65, 1, 64, E, ubp0,
                                          2, 1, hc, nul, 1, rbf, h0);
      // ===== layer 1 (x = h0, Cin=64, Ctot=128) =====
      chain(h1);
      kgc<128, CB><<<NN, 256, 0, stream>>>(h1, P1, P2, gwp1, 128, 64, 64, E, nullptr,
                                           0, 0, zb, rbf, 0, nul, nul);
      chain(h0);
      kgc<128, CB><<<NN, 256, 0, stream>>>(h0, P1, P2, gwp1, 128, 0, 64, E, gbp1,
                                           1, 1, zb, rbf, 0, nul, nul);
      kgc<64, CB><<<NN, 256, 0, stream>>>(h0, P1, P2, uwp1, 128, 0, 64, E, nullptr,
                                          0, 0, hc, nul, 0, nul, nul);
      kmulz<<<EW, 256, 0, stream>>>(zb, h1, (int)NC);
      chain(zb);
      kgc<64, CB><<<NN, 256, 0, stream>>>(zb, P1, P2, uwp1, 128, 64, 64, E, ubp1,
                                          2, 1, hc, nul, 1, rbf, h1);
    }
    kfin<<<(CB * TT * NN + 255) / 256, 256, 0, stream>>>(h1, cw, cb, out, b0, CB);
  }
}

extern "C" void kernel_launch(void* const* d_in, const int* in_sizes, int n_in,
                              void* d_out, int out_size, void* d_ws, size_t ws_size,
                              hipStream_t stream) {
  const float* src  = (const float*)d_in[0];
  const float* E    = (const float*)d_in[1];
  const float* gwp0 = (const float*)d_in[2];
  const float* gbp0 = (const float*)d_in[3];
  const float* uwp0 = (const float*)d_in[4];
  const float* ubp0 = (const float*)d_in[5];
  const float* gwp1 = (const float*)d_in[6];
  const float* gbp1 = (const float*)d_in[7];
  const float* uwp1 = (const float*)d_in[8];
  const float* ubp1 = (const float*)d_in[9];
  const float* cw   = (const float*)d_in[10];
  const float* cb   = (const float*)d_in[11];
  float* out = (float*)d_out;
  (void)in_sizes; (void)n_in; (void)out_size;

  char* wsp = (char*)d_ws;
  size_t off = 0;
  f16* Mh = (f16*)(wsp + off); off += ((size_t)MR * NN * 2 + 255) & ~(size_t)255;
  f16* Ml = (f16*)(wsp + off); off += ((size_t)MR * NN * 2 + 255) & ~(size_t)255;
  size_t off0 = off;  // chunk area starts here (~32 MB static so far)
  // transient prologue buffers overlap the chunk area (dead before chunks start)
  float* A  = (float*)(wsp + off0);
  float* A2 = (float*)(wsp + off0 + (((size_t)NN * NN * 4 + 255) & ~(size_t)255));

  ka<<<NN, 256, 0, stream>>>(E, A);
  {
    dim3 g((NN + TM - 1) / TM, (NN + TM - 1) / TM);
    kg<<<g, 256, 0, stream>>>(A, A, A2, NN);
  }
  ksplitM<<<(MR * NN + 255) / 256, 256, 0, stream>>>(A, A2, Mh, Ml);

  // footprints (incl. 32MB static): CB=64 ~297MB, CB=32 ~165MB, CB=16 ~99MB
  if (ws_size >= (size_t)320 * 1000 * 1000) {
    run_chunks<64>(src, E, gwp0, gbp0, uwp0, ubp0, gwp1, gbp1, uwp1, ubp1,
                   cw, cb, out, Mh, Ml, wsp, off0, stream);
  } else if (ws_size >= (size_t)185 * 1000 * 1000) {
    run_chunks<32>(src, E, gwp0, gbp0, uwp0, ubp0, gwp1, gbp1, uwp1, ubp1,
                   cw, cb, out, Mh, Ml, wsp, off0, stream);
  } else {
    run_chunks<16>(src, E, gwp0, gbp0, uwp0, ubp0, gwp1, gbp1, uwp1, ubp1,
                   cw, cb, out, Mh, Ml, wsp, off0, stream);
  }
}